// Round 7
// baseline (455.995 us; speedup 1.0000x reference)
//
#include <hip/hip_runtime.h>
#include <hip/hip_bf16.h>

// B=4, S=2048, D=1024, H=8, HD=128, FF=4096
// R14: R13 + col-per-XCD dispatch mapping in gemm256. Theory: GEMMs are
//      staging-BW-bound at ~128 FLOP/B with the per-XCD working set (6MB)
//      blowing the 4MB L2 -> everything streams from L3 (~15 TB/s -> ~690 TF,
//      matches all 5 schedule nulls). New map pins ONE 0.5MB B col-panel per
//      XCD (L2-resident) while A streams: first dispatch generation (j<32)
//      puts XCD k exclusively on col k. Bijective per shape (ncols 16/12/4).
//      Everything else identical to R13 (438.0us, absmax 0.03125).

typedef float floatx4 __attribute__((ext_vector_type(4)));
typedef float floatx16 __attribute__((ext_vector_type(16)));
typedef short bf16x8 __attribute__((ext_vector_type(8)));

#define DEVI __device__ __forceinline__

typedef const __attribute__((address_space(1))) unsigned int* gas1_t;
typedef __attribute__((address_space(3))) unsigned int* las3_t;

DEVI void gll16(const void* g, void* l) {
  __builtin_amdgcn_global_load_lds((gas1_t)g, (las3_t)l, 16, 0, 0);
}

DEVI short bfbits(float f) {
  __hip_bfloat16 h = __float2bfloat16(f);
  return *reinterpret_cast<short*>(&h);
}

// pack two f32 -> two bf16 (round-half-up): 2 v_add + 1 v_perm
DEVI unsigned int packbf(float lo, float hi) {
  return __builtin_amdgcn_perm(__float_as_uint(hi) + 0x8000u,
                               __float_as_uint(lo) + 0x8000u,
                               0x07060302u);
}

// ---------------------------------------------------------------------------
// C[M,N] = A[M,K](bf16 rm) * BT[N,K](bf16 rm). 256x256 tile, BK=64,
// 512 threads = 8 waves (2M x 4N), per-wave C = 128x64.
// LDS 128KB: A-half slots Ah[h][buf] (16KB), B-half slots Bh[h][buf] (16KB).
// Per tile t (cb = t&1):
//   half1: issue Ah1(t+1)->nb; ds_read Ah0+B (16); MFMA m0-3 (32); barrier
//   half2: issue Ah0(t+2),B(t+2)->cb; ds_read Ah1 (8); MFMA m4-7 (32);
//          vmcnt(6) [tile t+1 resident, 6 newest stay in flight]; barrier
// Col-per-XCD map: XCD k = flat%8 works one B col-panel at a time (L2-pinned).
// EPI 0: C bf16, Q-cols pre-scaled; V-cols transposed into Vt (=Cb2)
// EPI 2: relu | EPI 4: split-K partial
// ---------------------------------------------------------------------------
template<int EPI, int SPLITK>
__global__ __launch_bounds__(512, 2) void gemm256(
    const __hip_bfloat16* __restrict__ A,
    const __hip_bfloat16* __restrict__ BT,
    __hip_bfloat16* __restrict__ Cb, __hip_bfloat16* __restrict__ Cb2,
    int M, int N, int K)
{
  __shared__ __align__(16) char lds[131072];
  const int tid = threadIdx.x;
  const int wave = tid >> 6, lane = tid & 63;
  const int lane15 = lane & 15, quad = lane >> 4;
  const int wm = wave >> 2, wn = wave & 3;            // 2 x 4 waves

  // Col-per-XCD mapping (gx==32; XCD = flat%8 by round-robin dispatch).
  // First generation (flat 0..255 -> j<32): XCD k owns col k exclusively.
  const int gx = gridDim.x;
  const int ncols = gridDim.y;
  const int flat = blockIdx.x + gx * blockIdx.y;
  const int xk = flat & 7, jj = flat >> 3;
  int rowi, coli;
  if (ncols == 16)      { coli = xk + ((jj >> 5) << 3); rowi = jj & 31; }
  else if (ncols == 12) { if (jj < 32) { coli = xk; rowi = jj; }
                          else { coli = 8 + (xk >> 1);
                                 rowi = ((xk & 1) << 4) + (jj - 32); } }
  else                  { coli = xk >> 1; rowi = ((xk & 1) << 4) + (jj & 15); }
  const int row0 = rowi * 256, col0 = coli * 256;

  const int Kh = K / SPLITK;
  const size_t kofs = (SPLITK > 1) ? (size_t)blockIdx.z * Kh : 0;
  const int NT = Kh >> 6;

  floatx4 acc[8][4] = {};

  // staging: 512 thr x 16B = 8KB = 64 rows of 128B per issue
  const int srow = tid >> 3;                          // 0..63
  const int sblk = (tid & 7) ^ (srow & 7);            // chunk XOR swizzle
  const __hip_bfloat16* Ag = A + (size_t)(row0 + srow) * K + kofs + sblk * 8;
  const __hip_bfloat16* Bg = BT + (size_t)(col0 + srow) * K + kofs + sblk * 8;

  // A-half h, M-part p (0: wm=0 rows, 1: wm=1 rows), K-tile kt, buffer bf_
  auto stA = [&](int h, int p, int kt, int bf_) {
    gll16(Ag + (size_t)(p * 128 + h * 64) * (size_t)K + (size_t)kt * 64,
          lds + ((h << 1) + bf_) * 16384 + p * 8192 + (tid << 4));
  };
  // B-half h (BT rows h*128..), quarter q, K-tile kt, buffer bf_
  auto stB = [&](int h, int q, int kt, int bf_) {
    gll16(Bg + (size_t)(h * 128 + q * 64) * (size_t)K + (size_t)kt * 64,
          lds + 65536 + ((h << 1) + bf_) * 16384 + q * 8192 + (tid << 4));
  };

  // fragment read geometry
  const int x7 = lane15 & 7;
  const int ck0 = (quad ^ x7) << 4;
  const int ck1 = ((4 + quad) ^ x7) << 4;
  const int aoff = (wm * 64 + lane15) * 128;          // within A-half slot
  const int boff = ((wn & 1) * 64 + lane15) * 128;    // within B-half slot
  const int bhalf = wn >> 1;

  // ---- prologue: tile0 complete + Ah0(1),B(1) left in flight ----
  stA(0, 0, 0, 0); stA(0, 1, 0, 0);                   // Ah0(0)
  stA(1, 0, 0, 0); stA(1, 1, 0, 0);                   // Ah1(0)
  stB(0, 0, 0, 0); stB(0, 1, 0, 0); stB(1, 0, 0, 0); stB(1, 1, 0, 0); // B(0)
  stA(0, 0, 1, 1); stA(0, 1, 1, 1);                   // Ah0(1)
  stB(0, 0, 1, 1); stB(0, 1, 1, 1); stB(1, 0, 1, 1); stB(1, 1, 1, 1); // B(1)
  asm volatile("s_waitcnt vmcnt(6)" ::: "memory");    // tile0 resident
  asm volatile("s_barrier" ::: "memory");

  for (int t = 0; t < NT; ++t) {
    const int cb = t & 1, nb = cb ^ 1;
    const char* As0 = lds + cb * 16384 + aoff;              // Ah0 slot
    const char* As1 = lds + (2 + cb) * 16384 + aoff;        // Ah1 slot
    const char* Bs_ = lds + 65536 + ((bhalf << 1) + cb) * 16384 + boff;

    // ---------------- half 1: m0-3 (reads Ah0[cb], B[cb]) ----------------
    if (t + 1 < NT) { stA(1, 0, t + 1, nb); stA(1, 1, t + 1, nb); } // Ah1(t+1)
    bf16x8 af[8], bq[8];
#pragma unroll
    for (int i = 0; i < 4; i++) {
      af[2 * i]     = *(const bf16x8*)(As0 + i * 2048 + ck0);
      af[2 * i + 1] = *(const bf16x8*)(As0 + i * 2048 + ck1);
    }
#pragma unroll
    for (int j = 0; j < 4; j++) {
      bq[2 * j]     = *(const bf16x8*)(Bs_ + j * 2048 + ck0);
      bq[2 * j + 1] = *(const bf16x8*)(Bs_ + j * 2048 + ck1);
    }
    __builtin_amdgcn_s_setprio(1);
#pragma unroll
    for (int i = 0; i < 4; i++)
#pragma unroll
      for (int j = 0; j < 4; j++) {
        acc[i][j] = __builtin_amdgcn_mfma_f32_16x16x32_bf16(af[2 * i],     bq[2 * j],     acc[i][j], 0, 0, 0);
        acc[i][j] = __builtin_amdgcn_mfma_f32_16x16x32_bf16(af[2 * i + 1], bq[2 * j + 1], acc[i][j], 0, 0, 0);
      }
    __builtin_amdgcn_s_setprio(0);
    asm volatile("s_barrier" ::: "memory");   // Ah0[cb],B[cb] reads done blockwide

    // ---------------- half 2: m4-7 (reads Ah1[cb]) ----------------
    if (t + 2 < NT) {
      stA(0, 0, t + 2, cb); stA(0, 1, t + 2, cb);                  // Ah0(t+2)
      stB(0, 0, t + 2, cb); stB(0, 1, t + 2, cb);
      stB(1, 0, t + 2, cb); stB(1, 1, t + 2, cb);                  // B(t+2)
    }
#pragma unroll
    for (int i = 0; i < 4; i++) {
      af[2 * i]     = *(const bf16x8*)(As1 + i * 2048 + ck0);
      af[2 * i + 1] = *(const bf16x8*)(As1 + i * 2048 + ck1);
    }
    __builtin_amdgcn_s_setprio(1);
#pragma unroll
    for (int i = 0; i < 4; i++)
#pragma unroll
      for (int j = 0; j < 4; j++) {
        acc[4 + i][j] = __builtin_amdgcn_mfma_f32_16x16x32_bf16(af[2 * i],     bq[2 * j],     acc[4 + i][j], 0, 0, 0);
        acc[4 + i][j] = __builtin_amdgcn_mfma_f32_16x16x32_bf16(af[2 * i + 1], bq[2 * j + 1], acc[4 + i][j], 0, 0, 0);
      }
    __builtin_amdgcn_s_setprio(0);
    if (t + 2 < NT) {
      asm volatile("s_waitcnt vmcnt(6)" ::: "memory");  // tile t+1 resident
    } else if (t + 1 < NT) {
      asm volatile("s_waitcnt vmcnt(0)" ::: "memory");  // tail: drain
    }
    asm volatile("s_barrier" ::: "memory");
  }

  // -------------------------- epilogue --------------------------
  __hip_bfloat16* Cp = (SPLITK > 1 && blockIdx.z) ? Cb2 : Cb;

  // qkv only: V-column detection (col0 % 768: 256 -> V=[0,128), 512 -> [128,256))
  int vstart = -1;
  bool vwave = false;
  if (EPI == 0) {
    const int cm = col0 % 768;
    vstart = (cm == 256) ? 0 : (cm == 512 ? 128 : -1);
    vwave = (vstart == 0) ? (wn < 2) : (vstart == 128 ? (wn >= 2) : false);
  }

  if (!(EPI == 0 && vwave)) {
#pragma unroll
    for (int i = 0; i < 8; i++) {
      const int mb = row0 + wm * 128 + i * 16 + quad * 4;
#pragma unroll
      for (int j = 0; j < 4; j++) {
        const int n = col0 + wn * 64 + j * 16 + lane15;
        // qkv only: scale Q-columns by 1/sqrt(128)*log2(e) for exp2 softmax
        const float fac = (EPI == 0 && (((n >> 7) % 3) == 0)) ? 0.12751729f : 1.f;
#pragma unroll
        for (int r = 0; r < 4; r++) {
          const size_t idx = (size_t)(mb + r) * N + n;
          const float v = acc[i][j][r];
          if (EPI == 0) {
            Cb[idx] = __float2bfloat16(v * fac);
          } else if (EPI == 2) {
            Cb[idx] = __float2bfloat16(v > 0.f ? v : 0.f);
          } else {
            Cp[idx] = __float2bfloat16(v);
          }
        }
      }
    }
  }

  if (EPI == 0 && vstart >= 0) {
    // V-transpose bounce: LDS[d][sloc] (d=0..127, sloc=0..255), 512B rows,
    // byte addr = d*512 + ((sloc*2) ^ ((d&7)<<4)); 16B-granule XOR keeps
    // 8B groups contiguous. Writes <=2-way banked; reads are a permutation
    // of a contiguous 512B row -> conflict-free; stores 8B-coalesced.
    if (vwave) {
      const int dbase = wn * 64 - vstart;   // 0 or 64
#pragma unroll
      for (int i = 0; i < 8; i++) {
        const int sloc = wm * 128 + i * 16 + quad * 4;
#pragma unroll
        for (int j = 0; j < 4; j++) {
          const int d = dbase + j * 16 + lane15;
          uint2 pk;
          pk.x = packbf(acc[i][j][0], acc[i][j][1]);
          pk.y = packbf(acc[i][j][2], acc[i][j][3]);
          *(uint2*)(lds + d * 512 + ((sloc * 2) ^ ((d & 7) << 4))) = pk;
        }
      }
    }
    asm volatile("s_barrier" ::: "memory");   // V tile resident in LDS
    const int b_ = row0 >> 11;                // batch
    const int s0 = row0 & 2047;               // token offset within batch
    const int hv = (col0 + vstart) / 384;     // head
    __hip_bfloat16* vtb = Cb2 + ((size_t)(b_ * 8 + hv) * 128) * 2048 + s0;
#pragma unroll
    for (int p = 0; p < 16; p++) {
      const int d = p * 8 + wave;             // wave reads one d-row per pass
      const uint2 v8 = *(const uint2*)(lds + d * 512 + ((lane * 8) ^ ((d & 7) << 4)));
      *(uint2*)(vtb + (size_t)d * 2048 + lane * 4) = v8;
    }
  }
}

// ---------------------------------------------------------------------------
// Flash attention, pipelined. Grid (32 bh, 16 qt), bh-major -> XCD locality.
// 4 waves; wave owns 32 q (q = wave*32 + l31). S^T = K*Q^T with K-tile rows
// staged bit2<->bit3-permuted: pf built fully in-lane. Q pre-scaled in qkv
// GEMM -> p = exp2(s) directly. 2 barriers/kt. (R7 version, verified 89.7us)
// ---------------------------------------------------------------------------
__global__ __launch_bounds__(256, 2) void attn_kernel(
    const __hip_bfloat16* __restrict__ qkv,
    const __hip_bfloat16* __restrict__ Vt,
    __hip_bfloat16* __restrict__ vals)
{
  __shared__ __hip_bfloat16 Ak[128 * 128];   // K tiles (row-permuted)
  __shared__ __hip_bfloat16 Bq[128 * 128];   // Q, then V tiles

  const int tid = threadIdx.x;
  const int wave = tid >> 6, lane = tid & 63;
  const int l31 = lane & 31, l5 = lane >> 5;
  const int bh = blockIdx.x, qt = blockIdx.y;
  const int b = bh >> 3, h = bh & 7;
  const size_t tokbase = (size_t)b * 2048;

  const int sw8 = ((tid & 15) ^ (tid >> 4)) * 8;
  const int srow = tid >> 4;
  // bit2<->bit3 swap of the tile-local staging row (K only)
  const int srowp = (srow & 3) | ((srow << 1) & 8) | ((srow >> 1) & 4);
  const __hip_bfloat16* qg  = qkv + (tokbase + qt * 128) * 3072 + h * 384 + sw8;
  const __hip_bfloat16* kg0 = qkv + tokbase * 3072 + h * 384 + 128 + sw8;
  const __hip_bfloat16* vg0 = Vt + (size_t)bh * 128 * 2048 + sw8;

  // stage Q -> Bq
#pragma unroll
  for (int rd = 0; rd < 8; rd++)
    gll16(qg + (size_t)(rd * 16 + srow) * 3072, (char*)Bq + rd * 4096 + tid * 16);
  __syncthreads();

  const int rx = l31 & 15;
  bf16x8 qf[8];
  {
    const char* qb = (const char*)Bq + (wave * 32 + l31) * 256;
#pragma unroll
    for (int ks = 0; ks < 8; ks++)
      qf[ks] = *(const bf16x8*)(qb + (((ks * 2 + l5) ^ rx) << 4));
  }
  // stage K0 -> Ak (permuted rows)
#pragma unroll
  for (int rd = 0; rd < 8; rd++)
    gll16(kg0 + (size_t)(rd * 16 + srowp) * 3072, (char*)Ak + rd * 4096 + tid * 16);
  __syncthreads();   // qf reads done, K0 resident

  floatx16 oacc[4] = {};
  float lsum = 0.f;

  for (int kt = 0; kt < 16; kt++) {
    if (kt) __syncthreads();   // PV reads of Bq done; K_kt staging drained

    // issue V_kt -> Bq; overlaps QK + softmax below
#pragma unroll
    for (int rd = 0; rd < 8; rd++)
      gll16(vg0 + (size_t)kt * 128 + (size_t)(rd * 16 + srow) * 2048,
            (char*)Bq + rd * 4096 + tid * 16);

    // S^T = K Q^T : D[s][q], col q = l31
    floatx16 sacc[4] = {};
#pragma unroll
    for (int ks = 0; ks < 8; ks++) {
      const int off = ((ks * 2 + l5) ^ rx) << 4;
      const char* kb = (const char*)Ak + l31 * 256 + off;
#pragma unroll
      for (int nt = 0; nt < 4; nt++) {
        const bf16x8 ak = *(const bf16x8*)(kb + nt * 8192);
        sacc[nt] = __builtin_amdgcn_mfma_f32_32x32x16_bf16(ak, qf[ks], sacc[nt], 0, 0, 0);
      }
    }

    // p = exp2(s); in-lane sum; in-lane B-frag construction (key perm)
    bf16x8 pf[8];
#pragma unroll
    for (int c = 0; c < 8; c++) {
      const int nt = c >> 1, bi = (c & 1) * 8;
      const float p0 = exp2f(sacc[nt][bi + 0]);
      const float p1 = exp2f(sacc[nt][bi + 1]);
      const float p2 = exp2f(sacc[nt][bi + 2]);
      const float p3 = exp2f(sacc[nt][bi + 3]);
      const float p4 = exp2f(sacc[nt][bi + 4]);
      const float p5 = exp2f(sacc[nt][bi + 5]);
      const float p6 = exp2f(sacc[nt][bi + 6]);
      const float p7 = exp2f(sacc[nt][bi + 7]);
      lsum += ((p0 + p1) + (p2 + p3)) + ((p4 + p5) + (p6 + p7));
      union { uint4 u; bf16x8 v; } w;
      w.u.x = packbf(p0, p1); w.u.y = packbf(p2, p3);
      w.u.z = packbf(p4, p5); w.u.w = packbf(p6, p7);
      pf[c] = w.v;
    }

    __syncthreads();   // V_kt resident; QK reads of Ak done
    if (kt < 15) {     // issue K_{kt+1} -> Ak; overlaps PV below
#pragma unroll
      for (int rd = 0; rd < 8; rd++)
        gll16(kg0 + (size_t)((kt + 1) * 128 + rd * 16 + srowp) * 3072,
              (char*)Ak + rd * 4096 + tid * 16);
    }

    // O^T[hd][q] += V^T P^T : A = Vt rows hd (Bq), B = pf
#pragma unroll
    for (int ks = 0; ks < 8; ks++) {
      const int off = ((ks * 2 + l5) ^ rx) << 4;
      const char* vb = (const char*)Bq + l31 * 256 + off;
#pragma unroll
      for (int nt = 0; nt < 4; nt++) {
        const bf16x8 av = *(const bf16x8*)(vb + nt * 8192);
        oacc[nt] = __builtin_amdgcn_mfma_f32_32x32x16_bf16(av, pf[ks], oacc[nt], 0, 0, 0);
      }
    }
  }

  lsum += __shfl_xor(lsum, 32);
  const float linv = 1.f / lsum;

  // D layout: col q = l31, row hd = 32nt + 8g + 4l5 + r3 -> 8B stores
  const size_t row = tokbase + (size_t)qt * 128 + wave * 32 + l31;
  __hip_bfloat16* vrow = vals + row * 1024 + h * 128 + 4 * l5;
#pragma unroll
  for (int nt = 0; nt < 4; nt++)
#pragma unroll
    for (int g = 0; g < 4; g++) {
      uint2 pk;
      pk.x = packbf(oacc[nt][g * 4 + 0] * linv, oacc[nt][g * 4 + 1] * linv);
      pk.y = packbf(oacc[nt][g * 4 + 2] * linv, oacc[nt][g * 4 + 3] * linv);
      *(uint2*)(vrow + nt * 32 + g * 8) = pk;
    }
}

// --------------------------- aux kernels -----------------------------------
// Merged prep: blocks [0,8192) cast x to bf16; rest transpose+cast weights.
__global__ __launch_bounds__(256) void prep_k(
    const float* __restrict__ x, __hip_bfloat16* __restrict__ xb,
    const float* __restrict__ qkvw, __hip_bfloat16* __restrict__ qkvT,
    const float* __restrict__ ow, __hip_bfloat16* __restrict__ oT,
    const float* __restrict__ f1, __hip_bfloat16* __restrict__ f1T,
    const float* __restrict__ f2, __hip_bfloat16* __restrict__ f2T)
{
  const int bid = blockIdx.x;
  if (bid < 8192) {
    const size_t i = (size_t)bid * 256 + threadIdx.x;
    const float4 v = ((const float4*)x)[i];
    short4 sv;
    sv.x = bfbits(v.x); sv.y = bfbits(v.y); sv.z = bfbits(v.z); sv.w = bfbits(v.w);
    ((short4*)xb)[i] = sv;
    return;
  }
  int t = bid - 8192;
  const float* W; __hip_bfloat16* WT; int K, N, nbx;
  if (t < 3072) { W = qkvw; WT = qkvT; K = 1024; N = 3072; nbx = 96; }
  else if (t < 3072 + 1024) { t -= 3072; W = ow; WT = oT; K = 1024; N = 1024; nbx = 32; }
  else if (t < 3072 + 1024 + 4096) { t -= 3072 + 1024; W = f1; WT = f1T; K = 1024; N = 4096; nbx = 128; }
  else { t -= 3072 + 1024 + 4096; W = f2; WT = f2T; K = 4096; N = 1024; nbx = 32; }
  __shared__ float tl[32][33];
  const int tx = threadIdx.x & 31, ty = threadIdx.x >> 5;
  const int n0 = (t % nbx) * 32, k0 = (t / nbx) * 32;
#pragma unroll
  for (int i = 0; i < 4; i++)
    tl[ty + i * 8][tx] = W[(size_t)(k0 + ty + i * 8) * N + n0 + tx];
  __syncthreads();
#pragma unroll
  for (int i = 0; i < 4; i++)
    WT[(size_t)(n0 + ty + i * 8) * K + k0 + tx] = __float2bfloat16(tl[tx][ty + i * 8]);
}

// Fused split-K reduce (bf16 partials) + bf16 residual + LayerNorm over 1024.
template<bool FINAL>
__global__ __launch_bounds__(256) void ln_red_k(
    const __hip_bfloat16* __restrict__ p0, const __hip_bfloat16* __restrict__ p1,
    const __hip_bfloat16* __restrict__ res,
    __hip_bfloat16* __restrict__ ob, float* __restrict__ of) {
  const int row = blockIdx.x, tid = threadIdx.x;
  const size_t base = (size_t)row * 1024;
  const short4 a4 = ((const short4*)(p0 + base))[tid];
  const short4 b4 = ((const short4*)(p1 + base))[tid];
  const short4 r4 = ((const short4*)(res + base))[tid];
#define BF(x) __bfloat162float(*(const __hip_bfloat16*)&(x))
  float4 v;
  v.x = BF(a4.x) + BF(b4.x) + BF(r4.x);
  v.y = BF(a4.y) + BF(b4.y) + BF(r4.y);
  v.z = BF(a4.z) + BF(b4.z) + BF(r4.z);
  v.w = BF(a4.w) + BF(b4.w) + BF(r4.w);
#undef BF
  float s = v.x + v.y + v.z + v.w;
  float q = v.x * v.x + v.y * v.y + v.z * v.z + v.w * v.w;
#pragma unroll
  for (int off = 32; off; off >>= 1) { s += __shfl_xor(s, off); q += __shfl_xor(q, off); }
  __shared__ float ss[4], sq[4];
  const int wave = tid >> 6;
  if ((tid & 63) == 0) { ss[wave] = s; sq[wave] = q; }
  __syncthreads();
  s = ss[0] + ss[1] + ss[2] + ss[3];
  q = sq[0] + sq[1] + sq[2] + sq[3];
  const float mean = s * (1.f / 1024.f);
  const float var = q * (1.f / 1024.f) - mean * mean;
  const float rstd = rsqrtf(var + 1e-5f);
  float4 o;
  o.x = (v.x - mean) * rstd; o.y = (v.y - mean) * rstd;
  o.z = (v.z - mean) * rstd; o.w = (v.w - mean) * rstd;
  if (FINAL) {
    ((float4*)(of + base))[tid] = o;
  } else {
    short4 sv;
    sv.x = bfbits(o.x); sv.y = bfbits(o.y); sv.z = bfbits(o.z); sv.w = bfbits(o.w);
    ((short4*)(ob + base))[tid] = sv;
  }
}

// ---------------------------------------------------------------------------
extern "C" void kernel_launch(void* const* d_in, const int* in_sizes, int n_in,
                              void* d_out, int out_size, void* d_ws, size_t ws_size,
                              hipStream_t stream) {
  const float* x    = (const float*)d_in[0];
  const float* qkvw = (const float*)d_in[1];
  const float* ow   = (const float*)d_in[2];
  const float* f1   = (const float*)d_in[3];
  const float* f2   = (const float*)d_in[4];
  float* out = (float*)d_out;

  char* ws = (char*)d_ws;
  const size_t MB = 1024 * 1024;
  // ws layout (152 MB):
  __hip_bfloat16* xb   = (__hip_bfloat16*)(ws);             // 0..16   (alive to LN1)
  __hip_bfloat16* vals = (__hip_bfloat16*)(ws + 16 * MB);   // 16..32  (attn out, to o_proj)
  __hip_bfloat16* P1f  = (__hip_bfloat16*)(ws + 16 * MB);   // 16..32  (ff2 z=1, after vals dead)
  __hip_bfloat16* qkvT = (__hip_bfloat16*)(ws + 32 * MB);   // 32..38
  __hip_bfloat16* oT   = (__hip_bfloat16*)(ws + 38 * MB);   // 38..40
  __hip_bfloat16* f1T  = (__hip_bfloat16*)(ws + 40 * MB);   // 40..48
  __hip_bfloat16* f2T  = (__hip_bfloat16*)(ws + 48 * MB);   // 48..56
  __hip_bfloat16* qkvb = (__hip_bfloat16*)(ws + 56 * MB);   // 56..104 (to attn)
  __hip_bfloat16* P0o  = (__hip_bfloat16*)(ws + 56 * MB);   // 56..72  (after qkvb dead)
  __hip_bfloat16* P1o  = (__hip_bfloat16*)(ws + 72 * MB);   // 72..88
  __hip_bfloat16* hmid = (__hip_bfloat16*)(ws + 56 * MB);   // 56..120 (after LN1)
  __hip_bfloat16* Vt   = (__hip_bfloat16*)(ws + 104 * MB);  // 104..120 (to attn)
  __hip_bfloat16* x1b  = (__hip_bfloat16*)(ws + 120 * MB);  // 120..136 (to final LN)
  __hip_bfloat16* P0f  = (__hip_bfloat16*)(ws + 136 * MB);  // 136..152
  (void)in_sizes; (void)n_in; (void)out_size; (void)ws_size;

  // merged prep: x cast (8192 blocks) + 4 weight transposes (12288 blocks)
  prep_k<<<20480, 256, 0, stream>>>(x, xb, qkvw, qkvT, ow, oT, f1, f1T, f2, f2T);
  // qkv = x @ qkv_proj (bf16; Q-cols pre-scaled; V transposed into Vt)
  gemm256<0, 1><<<dim3(32, 12, 1), 512, 0, stream>>>(xb, qkvT, qkvb, Vt,
                                                     8192, 3072, 1024);
  attn_kernel<<<dim3(32, 16), 256, 0, stream>>>(qkvb, Vt, vals);
  // o_proj partials (split-K=2, bf16)
  gemm256<4, 2><<<dim3(32, 4, 2), 512, 0, stream>>>(vals, oT, P0o, P1o,
                                                    8192, 1024, 1024);
  // x1 = LN(P0o + P1o + x) (bf16)
  ln_red_k<false><<<8192, 256, 0, stream>>>(P0o, P1o, xb, x1b, nullptr);
  // h = relu(x1 @ ff1) (bf16)
  gemm256<2, 1><<<dim3(32, 16, 1), 512, 0, stream>>>(x1b, f1T, hmid, nullptr,
                                                     8192, 4096, 1024);
  // ff2 partials (split-K=2, bf16)
  gemm256<4, 2><<<dim3(32, 4, 2), 512, 0, stream>>>(hmid, f2T, P0f, P1f,
                                                    8192, 1024, 4096);
  // out = LN(P0f + P1f + x1) (f32)
  ln_red_k<true><<<8192, 256, 0, stream>>>(P0f, P1f, x1b, nullptr, out);
}

// Round 8
// 446.899 us; speedup vs baseline: 1.0204x; 1.0204x over previous
//
#include <hip/hip_runtime.h>
#include <hip/hip_bf16.h>

// B=4, S=2048, D=1024, H=8, HD=128, FF=4096
// R15: GEMM reverted to R13 exactly (438.0us best; R14 col-per-XCD map
//      regressed +18us by destroying A-panel reuse -> GEMM closed).
//      Attn: lsum tree (56 VALU adds/kt) moved to MFMA via all-ones A-frag
//      (lacc = sum_ks mfma(ones, pf[ks])) -> lsum lands in-lane, shfl gone.
//      prep_k: x-cast vectorized to short8 (4096 blocks, same RNE rounding).

typedef float floatx4 __attribute__((ext_vector_type(4)));
typedef float floatx16 __attribute__((ext_vector_type(16)));
typedef short bf16x8 __attribute__((ext_vector_type(8)));

#define DEVI __device__ __forceinline__

typedef const __attribute__((address_space(1))) unsigned int* gas1_t;
typedef __attribute__((address_space(3))) unsigned int* las3_t;

DEVI void gll16(const void* g, void* l) {
  __builtin_amdgcn_global_load_lds((gas1_t)g, (las3_t)l, 16, 0, 0);
}

DEVI short bfbits(float f) {
  __hip_bfloat16 h = __float2bfloat16(f);
  return *reinterpret_cast<short*>(&h);
}

// pack two f32 -> two bf16 (round-half-up): 2 v_add + 1 v_perm
DEVI unsigned int packbf(float lo, float hi) {
  return __builtin_amdgcn_perm(__float_as_uint(hi) + 0x8000u,
                               __float_as_uint(lo) + 0x8000u,
                               0x07060302u);
}

// ---------------------------------------------------------------------------
// C[M,N] = A[M,K](bf16 rm) * BT[N,K](bf16 rm). 256x256 tile, BK=64,
// 512 threads = 8 waves (2M x 4N), per-wave C = 128x64.
// LDS 128KB: A-half slots Ah[h][buf] (16KB), B-half slots Bh[h][buf] (16KB).
// Per tile t (cb = t&1):
//   half1: issue Ah1(t+1)->nb; ds_read Ah0+B (16); MFMA m0-3 (32); barrier
//   half2: issue Ah0(t+2),B(t+2)->cb; ds_read Ah1 (8); MFMA m4-7 (32);
//          vmcnt(6) [tile t+1 resident, 6 newest stay in flight]; barrier
// XCD remap: xcd owns gx/8 consecutive rows, sweeps cols col-major.
// EPI 0: C bf16, Q-cols pre-scaled; V-cols transposed into Vt (=Cb2)
// EPI 2: relu | EPI 4: split-K partial
// ---------------------------------------------------------------------------
template<int EPI, int SPLITK>
__global__ __launch_bounds__(512, 2) void gemm256(
    const __hip_bfloat16* __restrict__ A,
    const __hip_bfloat16* __restrict__ BT,
    __hip_bfloat16* __restrict__ Cb, __hip_bfloat16* __restrict__ Cb2,
    int M, int N, int K)
{
  __shared__ __align__(16) char lds[131072];
  const int tid = threadIdx.x;
  const int wave = tid >> 6, lane = tid & 63;
  const int lane15 = lane & 15, quad = lane >> 4;
  const int wm = wave >> 2, wn = wave & 3;            // 2 x 4 waves

  // XCD-clustered tile remap (requires gridDim.x % 8 == 0; holds: gx=32)
  const int gx = gridDim.x;
  const int rpx = gx >> 3;                            // rows per XCD
  const int flat = blockIdx.x + gx * blockIdx.y;
  const int xcd = flat & 7;
  const int ii  = flat >> 3;
  const int row0 = (xcd * rpx + (ii % rpx)) * 256;
  const int col0 = (ii / rpx) * 256;

  const int Kh = K / SPLITK;
  const size_t kofs = (SPLITK > 1) ? (size_t)blockIdx.z * Kh : 0;
  const int NT = Kh >> 6;

  floatx4 acc[8][4] = {};

  // staging: 512 thr x 16B = 8KB = 64 rows of 128B per issue
  const int srow = tid >> 3;                          // 0..63
  const int sblk = (tid & 7) ^ (srow & 7);            // chunk XOR swizzle
  const __hip_bfloat16* Ag = A + (size_t)(row0 + srow) * K + kofs + sblk * 8;
  const __hip_bfloat16* Bg = BT + (size_t)(col0 + srow) * K + kofs + sblk * 8;

  // A-half h, M-part p (0: wm=0 rows, 1: wm=1 rows), K-tile kt, buffer bf_
  auto stA = [&](int h, int p, int kt, int bf_) {
    gll16(Ag + (size_t)(p * 128 + h * 64) * (size_t)K + (size_t)kt * 64,
          lds + ((h << 1) + bf_) * 16384 + p * 8192 + (tid << 4));
  };
  // B-half h (BT rows h*128..), quarter q, K-tile kt, buffer bf_
  auto stB = [&](int h, int q, int kt, int bf_) {
    gll16(Bg + (size_t)(h * 128 + q * 64) * (size_t)K + (size_t)kt * 64,
          lds + 65536 + ((h << 1) + bf_) * 16384 + q * 8192 + (tid << 4));
  };

  // fragment read geometry
  const int x7 = lane15 & 7;
  const int ck0 = (quad ^ x7) << 4;
  const int ck1 = ((4 + quad) ^ x7) << 4;
  const int aoff = (wm * 64 + lane15) * 128;          // within A-half slot
  const int boff = ((wn & 1) * 64 + lane15) * 128;    // within B-half slot
  const int bhalf = wn >> 1;

  // ---- prologue: tile0 complete + Ah0(1),B(1) left in flight ----
  stA(0, 0, 0, 0); stA(0, 1, 0, 0);                   // Ah0(0)
  stA(1, 0, 0, 0); stA(1, 1, 0, 0);                   // Ah1(0)
  stB(0, 0, 0, 0); stB(0, 1, 0, 0); stB(1, 0, 0, 0); stB(1, 1, 0, 0); // B(0)
  stA(0, 0, 1, 1); stA(0, 1, 1, 1);                   // Ah0(1)
  stB(0, 0, 1, 1); stB(0, 1, 1, 1); stB(1, 0, 1, 1); stB(1, 1, 1, 1); // B(1)
  asm volatile("s_waitcnt vmcnt(6)" ::: "memory");    // tile0 resident
  asm volatile("s_barrier" ::: "memory");

  for (int t = 0; t < NT; ++t) {
    const int cb = t & 1, nb = cb ^ 1;
    const char* As0 = lds + cb * 16384 + aoff;              // Ah0 slot
    const char* As1 = lds + (2 + cb) * 16384 + aoff;        // Ah1 slot
    const char* Bs_ = lds + 65536 + ((bhalf << 1) + cb) * 16384 + boff;

    // ---------------- half 1: m0-3 (reads Ah0[cb], B[cb]) ----------------
    if (t + 1 < NT) { stA(1, 0, t + 1, nb); stA(1, 1, t + 1, nb); } // Ah1(t+1)
    bf16x8 af[8], bq[8];
#pragma unroll
    for (int i = 0; i < 4; i++) {
      af[2 * i]     = *(const bf16x8*)(As0 + i * 2048 + ck0);
      af[2 * i + 1] = *(const bf16x8*)(As0 + i * 2048 + ck1);
    }
#pragma unroll
    for (int j = 0; j < 4; j++) {
      bq[2 * j]     = *(const bf16x8*)(Bs_ + j * 2048 + ck0);
      bq[2 * j + 1] = *(const bf16x8*)(Bs_ + j * 2048 + ck1);
    }
    __builtin_amdgcn_s_setprio(1);
#pragma unroll
    for (int i = 0; i < 4; i++)
#pragma unroll
      for (int j = 0; j < 4; j++) {
        acc[i][j] = __builtin_amdgcn_mfma_f32_16x16x32_bf16(af[2 * i],     bq[2 * j],     acc[i][j], 0, 0, 0);
        acc[i][j] = __builtin_amdgcn_mfma_f32_16x16x32_bf16(af[2 * i + 1], bq[2 * j + 1], acc[i][j], 0, 0, 0);
      }
    __builtin_amdgcn_s_setprio(0);
    asm volatile("s_barrier" ::: "memory");   // Ah0[cb],B[cb] reads done blockwide

    // ---------------- half 2: m4-7 (reads Ah1[cb]) ----------------
    if (t + 2 < NT) {
      stA(0, 0, t + 2, cb); stA(0, 1, t + 2, cb);                  // Ah0(t+2)
      stB(0, 0, t + 2, cb); stB(0, 1, t + 2, cb);
      stB(1, 0, t + 2, cb); stB(1, 1, t + 2, cb);                  // B(t+2)
    }
#pragma unroll
    for (int i = 0; i < 4; i++) {
      af[2 * i]     = *(const bf16x8*)(As1 + i * 2048 + ck0);
      af[2 * i + 1] = *(const bf16x8*)(As1 + i * 2048 + ck1);
    }
    __builtin_amdgcn_s_setprio(1);
#pragma unroll
    for (int i = 0; i < 4; i++)
#pragma unroll
      for (int j = 0; j < 4; j++) {
        acc[4 + i][j] = __builtin_amdgcn_mfma_f32_16x16x32_bf16(af[2 * i],     bq[2 * j],     acc[4 + i][j], 0, 0, 0);
        acc[4 + i][j] = __builtin_amdgcn_mfma_f32_16x16x32_bf16(af[2 * i + 1], bq[2 * j + 1], acc[4 + i][j], 0, 0, 0);
      }
    __builtin_amdgcn_s_setprio(0);
    if (t + 2 < NT) {
      asm volatile("s_waitcnt vmcnt(6)" ::: "memory");  // tile t+1 resident
    } else if (t + 1 < NT) {
      asm volatile("s_waitcnt vmcnt(0)" ::: "memory");  // tail: drain
    }
    asm volatile("s_barrier" ::: "memory");
  }

  // -------------------------- epilogue --------------------------
  __hip_bfloat16* Cp = (SPLITK > 1 && blockIdx.z) ? Cb2 : Cb;

  // qkv only: V-column detection (col0 % 768: 256 -> V=[0,128), 512 -> [128,256))
  int vstart = -1;
  bool vwave = false;
  if (EPI == 0) {
    const int cm = col0 % 768;
    vstart = (cm == 256) ? 0 : (cm == 512 ? 128 : -1);
    vwave = (vstart == 0) ? (wn < 2) : (vstart == 128 ? (wn >= 2) : false);
  }

  if (!(EPI == 0 && vwave)) {
#pragma unroll
    for (int i = 0; i < 8; i++) {
      const int mb = row0 + wm * 128 + i * 16 + quad * 4;
#pragma unroll
      for (int j = 0; j < 4; j++) {
        const int n = col0 + wn * 64 + j * 16 + lane15;
        // qkv only: scale Q-columns by 1/sqrt(128)*log2(e) for exp2 softmax
        const float fac = (EPI == 0 && (((n >> 7) % 3) == 0)) ? 0.12751729f : 1.f;
#pragma unroll
        for (int r = 0; r < 4; r++) {
          const size_t idx = (size_t)(mb + r) * N + n;
          const float v = acc[i][j][r];
          if (EPI == 0) {
            Cb[idx] = __float2bfloat16(v * fac);
          } else if (EPI == 2) {
            Cb[idx] = __float2bfloat16(v > 0.f ? v : 0.f);
          } else {
            Cp[idx] = __float2bfloat16(v);
          }
        }
      }
    }
  }

  if (EPI == 0 && vstart >= 0) {
    // V-transpose bounce: LDS[d][sloc] (d=0..127, sloc=0..255), 512B rows,
    // byte addr = d*512 + ((sloc*2) ^ ((d&7)<<4)); 16B-granule XOR keeps
    // 8B groups contiguous. Writes <=2-way banked; reads are a permutation
    // of a contiguous 512B row -> conflict-free; stores 8B-coalesced.
    if (vwave) {
      const int dbase = wn * 64 - vstart;   // 0 or 64
#pragma unroll
      for (int i = 0; i < 8; i++) {
        const int sloc = wm * 128 + i * 16 + quad * 4;
#pragma unroll
        for (int j = 0; j < 4; j++) {
          const int d = dbase + j * 16 + lane15;
          uint2 pk;
          pk.x = packbf(acc[i][j][0], acc[i][j][1]);
          pk.y = packbf(acc[i][j][2], acc[i][j][3]);
          *(uint2*)(lds + d * 512 + ((sloc * 2) ^ ((d & 7) << 4))) = pk;
        }
      }
    }
    asm volatile("s_barrier" ::: "memory");   // V tile resident in LDS
    const int b_ = row0 >> 11;                // batch
    const int s0 = row0 & 2047;               // token offset within batch
    const int hv = (col0 + vstart) / 384;     // head
    __hip_bfloat16* vtb = Cb2 + ((size_t)(b_ * 8 + hv) * 128) * 2048 + s0;
#pragma unroll
    for (int p = 0; p < 16; p++) {
      const int d = p * 8 + wave;             // wave reads one d-row per pass
      const uint2 v8 = *(const uint2*)(lds + d * 512 + ((lane * 8) ^ ((d & 7) << 4)));
      *(uint2*)(vtb + (size_t)d * 2048 + lane * 4) = v8;
    }
  }
}

// ---------------------------------------------------------------------------
// Flash attention, pipelined. Grid (32 bh, 16 qt), bh-major -> XCD locality.
// 4 waves; wave owns 32 q (q = wave*32 + l31). S^T = K*Q^T with K-tile rows
// staged bit2<->bit3-permuted: pf built fully in-lane. Q pre-scaled in qkv
// GEMM -> p = exp2(s) directly. 2 barriers/kt.
// R15: lsum via MFMA ones-trick (lacc = sum_ks mfma(ones, pf[ks])) -> 56
//      VALU adds/kt and the final shfl removed; lsum lands in-lane (col l31).
// ---------------------------------------------------------------------------
__global__ __launch_bounds__(256, 2) void attn_kernel(
    const __hip_bfloat16* __restrict__ qkv,
    const __hip_bfloat16* __restrict__ Vt,
    __hip_bfloat16* __restrict__ vals)
{
  __shared__ __hip_bfloat16 Ak[128 * 128];   // K tiles (row-permuted)
  __shared__ __hip_bfloat16 Bq[128 * 128];   // Q, then V tiles

  const int tid = threadIdx.x;
  const int wave = tid >> 6, lane = tid & 63;
  const int l31 = lane & 31, l5 = lane >> 5;
  const int bh = blockIdx.x, qt = blockIdx.y;
  const int b = bh >> 3, h = bh & 7;
  const size_t tokbase = (size_t)b * 2048;

  const int sw8 = ((tid & 15) ^ (tid >> 4)) * 8;
  const int srow = tid >> 4;
  // bit2<->bit3 swap of the tile-local staging row (K only)
  const int srowp = (srow & 3) | ((srow << 1) & 8) | ((srow >> 1) & 4);
  const __hip_bfloat16* qg  = qkv + (tokbase + qt * 128) * 3072 + h * 384 + sw8;
  const __hip_bfloat16* kg0 = qkv + tokbase * 3072 + h * 384 + 128 + sw8;
  const __hip_bfloat16* vg0 = Vt + (size_t)bh * 128 * 2048 + sw8;

  // stage Q -> Bq
#pragma unroll
  for (int rd = 0; rd < 8; rd++)
    gll16(qg + (size_t)(rd * 16 + srow) * 3072, (char*)Bq + rd * 4096 + tid * 16);
  __syncthreads();

  const int rx = l31 & 15;
  bf16x8 qf[8];
  {
    const char* qb = (const char*)Bq + (wave * 32 + l31) * 256;
#pragma unroll
    for (int ks = 0; ks < 8; ks++)
      qf[ks] = *(const bf16x8*)(qb + (((ks * 2 + l5) ^ rx) << 4));
  }
  // stage K0 -> Ak (permuted rows)
#pragma unroll
  for (int rd = 0; rd < 8; rd++)
    gll16(kg0 + (size_t)(rd * 16 + srowp) * 3072, (char*)Ak + rd * 4096 + tid * 16);
  __syncthreads();   // qf reads done, K0 resident

  floatx16 oacc[4] = {};
  floatx16 lacc = {};
  bf16x8 ones;
#pragma unroll
  for (int z = 0; z < 8; z++) ones[z] = (short)0x3F80;   // bf16 1.0

  for (int kt = 0; kt < 16; kt++) {
    if (kt) __syncthreads();   // PV reads of Bq done; K_kt staging drained

    // issue V_kt -> Bq; overlaps QK + softmax below
#pragma unroll
    for (int rd = 0; rd < 8; rd++)
      gll16(vg0 + (size_t)kt * 128 + (size_t)(rd * 16 + srow) * 2048,
            (char*)Bq + rd * 4096 + tid * 16);

    // S^T = K Q^T : D[s][q], col q = l31
    floatx16 sacc[4] = {};
#pragma unroll
    for (int ks = 0; ks < 8; ks++) {
      const int off = ((ks * 2 + l5) ^ rx) << 4;
      const char* kb = (const char*)Ak + l31 * 256 + off;
#pragma unroll
      for (int nt = 0; nt < 4; nt++) {
        const bf16x8 ak = *(const bf16x8*)(kb + nt * 8192);
        sacc[nt] = __builtin_amdgcn_mfma_f32_32x32x16_bf16(ak, qf[ks], sacc[nt], 0, 0, 0);
      }
    }

    // p = exp2(s); in-lane B-frag construction (key perm); sum via MFMA below
    bf16x8 pf[8];
#pragma unroll
    for (int c = 0; c < 8; c++) {
      const int nt = c >> 1, bi = (c & 1) * 8;
      const float p0 = exp2f(sacc[nt][bi + 0]);
      const float p1 = exp2f(sacc[nt][bi + 1]);
      const float p2 = exp2f(sacc[nt][bi + 2]);
      const float p3 = exp2f(sacc[nt][bi + 3]);
      const float p4 = exp2f(sacc[nt][bi + 4]);
      const float p5 = exp2f(sacc[nt][bi + 5]);
      const float p6 = exp2f(sacc[nt][bi + 6]);
      const float p7 = exp2f(sacc[nt][bi + 7]);
      union { uint4 u; bf16x8 v; } w;
      w.u.x = packbf(p0, p1); w.u.y = packbf(p2, p3);
      w.u.z = packbf(p4, p5); w.u.w = packbf(p6, p7);
      pf[c] = w.v;
    }

    __syncthreads();   // V_kt resident; QK reads of Ak done
    if (kt < 15) {     // issue K_{kt+1} -> Ak; overlaps PV below
#pragma unroll
      for (int rd = 0; rd < 8; rd++)
        gll16(kg0 + (size_t)((kt + 1) * 128 + rd * 16 + srowp) * 3072,
              (char*)Ak + rd * 4096 + tid * 16);
    }

    // O^T[hd][q] += V^T P^T : A = Vt rows hd (Bq), B = pf
    // lacc row m = sum_s P^T[s][q] (ones-A) -> lsum(q) in-lane
#pragma unroll
    for (int ks = 0; ks < 8; ks++) {
      const int off = ((ks * 2 + l5) ^ rx) << 4;
      const char* vb = (const char*)Bq + l31 * 256 + off;
#pragma unroll
      for (int nt = 0; nt < 4; nt++) {
        const bf16x8 av = *(const bf16x8*)(vb + nt * 8192);
        oacc[nt] = __builtin_amdgcn_mfma_f32_32x32x16_bf16(av, pf[ks], oacc[nt], 0, 0, 0);
      }
      lacc = __builtin_amdgcn_mfma_f32_32x32x16_bf16(ones, pf[ks], lacc, 0, 0, 0);
    }
  }

  const float linv = 1.f / lacc[0];

  // D layout: col q = l31, row hd = 32nt + 8g + 4l5 + r3 -> 8B stores
  const size_t row = tokbase + (size_t)qt * 128 + wave * 32 + l31;
  __hip_bfloat16* vrow = vals + row * 1024 + h * 128 + 4 * l5;
#pragma unroll
  for (int nt = 0; nt < 4; nt++)
#pragma unroll
    for (int g = 0; g < 4; g++) {
      uint2 pk;
      pk.x = packbf(oacc[nt][g * 4 + 0] * linv, oacc[nt][g * 4 + 1] * linv);
      pk.y = packbf(oacc[nt][g * 4 + 2] * linv, oacc[nt][g * 4 + 3] * linv);
      *(uint2*)(vrow + nt * 32 + g * 8) = pk;
    }
}

// --------------------------- aux kernels -----------------------------------
// Merged prep: blocks [0,4096) cast x to bf16 (short8); rest transpose weights.
__global__ __launch_bounds__(256) void prep_k(
    const float* __restrict__ x, __hip_bfloat16* __restrict__ xb,
    const float* __restrict__ qkvw, __hip_bfloat16* __restrict__ qkvT,
    const float* __restrict__ ow, __hip_bfloat16* __restrict__ oT,
    const float* __restrict__ f1, __hip_bfloat16* __restrict__ f1T,
    const float* __restrict__ f2, __hip_bfloat16* __restrict__ f2T)
{
  const int bid = blockIdx.x;
  if (bid < 4096) {
    const size_t i = (size_t)bid * 256 + threadIdx.x;
    const float4 a = ((const float4*)x)[2 * i];
    const float4 c = ((const float4*)x)[2 * i + 1];
    uint4 sv;
    sv.x = (unsigned int)(unsigned short)bfbits(a.x) | ((unsigned int)(unsigned short)bfbits(a.y) << 16);
    sv.y = (unsigned int)(unsigned short)bfbits(a.z) | ((unsigned int)(unsigned short)bfbits(a.w) << 16);
    sv.z = (unsigned int)(unsigned short)bfbits(c.x) | ((unsigned int)(unsigned short)bfbits(c.y) << 16);
    sv.w = (unsigned int)(unsigned short)bfbits(c.z) | ((unsigned int)(unsigned short)bfbits(c.w) << 16);
    ((uint4*)xb)[i] = sv;
    return;
  }
  int t = bid - 4096;
  const float* W; __hip_bfloat16* WT; int K, N, nbx;
  if (t < 3072) { W = qkvw; WT = qkvT; K = 1024; N = 3072; nbx = 96; }
  else if (t < 3072 + 1024) { t -= 3072; W = ow; WT = oT; K = 1024; N = 1024; nbx = 32; }
  else if (t < 3072 + 1024 + 4096) { t -= 3072 + 1024; W = f1; WT = f1T; K = 1024; N = 4096; nbx = 128; }
  else { t -= 3072 + 1024 + 4096; W = f2; WT = f2T; K = 4096; N = 1024; nbx = 32; }
  __shared__ float tl[32][33];
  const int tx = threadIdx.x & 31, ty = threadIdx.x >> 5;
  const int n0 = (t % nbx) * 32, k0 = (t / nbx) * 32;
#pragma unroll
  for (int i = 0; i < 4; i++)
    tl[ty + i * 8][tx] = W[(size_t)(k0 + ty + i * 8) * N + n0 + tx];
  __syncthreads();
#pragma unroll
  for (int i = 0; i < 4; i++)
    WT[(size_t)(n0 + ty + i * 8) * K + k0 + tx] = __float2bfloat16(tl[tx][ty + i * 8]);
}

// Fused split-K reduce (bf16 partials) + bf16 residual + LayerNorm over 1024.
template<bool FINAL>
__global__ __launch_bounds__(256) void ln_red_k(
    const __hip_bfloat16* __restrict__ p0, const __hip_bfloat16* __restrict__ p1,
    const __hip_bfloat16* __restrict__ res,
    __hip_bfloat16* __restrict__ ob, float* __restrict__ of) {
  const int row = blockIdx.x, tid = threadIdx.x;
  const size_t base = (size_t)row * 1024;
  const short4 a4 = ((const short4*)(p0 + base))[tid];
  const short4 b4 = ((const short4*)(p1 + base))[tid];
  const short4 r4 = ((const short4*)(res + base))[tid];
#define BF(x) __bfloat162float(*(const __hip_bfloat16*)&(x))
  float4 v;
  v.x = BF(a4.x) + BF(b4.x) + BF(r4.x);
  v.y = BF(a4.y) + BF(b4.y) + BF(r4.y);
  v.z = BF(a4.z) + BF(b4.z) + BF(r4.z);
  v.w = BF(a4.w) + BF(b4.w) + BF(r4.w);
#undef BF
  float s = v.x + v.y + v.z + v.w;
  float q = v.x * v.x + v.y * v.y + v.z * v.z + v.w * v.w;
#pragma unroll
  for (int off = 32; off; off >>= 1) { s += __shfl_xor(s, off); q += __shfl_xor(q, off); }
  __shared__ float ss[4], sq[4];
  const int wave = tid >> 6;
  if ((tid & 63) == 0) { ss[wave] = s; sq[wave] = q; }
  __syncthreads();
  s = ss[0] + ss[1] + ss[2] + ss[3];
  q = sq[0] + sq[1] + sq[2] + sq[3];
  const float mean = s * (1.f / 1024.f);
  const float var = q * (1.f / 1024.f) - mean * mean;
  const float rstd = rsqrtf(var + 1e-5f);
  float4 o;
  o.x = (v.x - mean) * rstd; o.y = (v.y - mean) * rstd;
  o.z = (v.z - mean) * rstd; o.w = (v.w - mean) * rstd;
  if (FINAL) {
    ((float4*)(of + base))[tid] = o;
  } else {
    short4 sv;
    sv.x = bfbits(o.x); sv.y = bfbits(o.y); sv.z = bfbits(o.z); sv.w = bfbits(o.w);
    ((short4*)(ob + base))[tid] = sv;
  }
}

// ---------------------------------------------------------------------------
extern "C" void kernel_launch(void* const* d_in, const int* in_sizes, int n_in,
                              void* d_out, int out_size, void* d_ws, size_t ws_size,
                              hipStream_t stream) {
  const float* x    = (const float*)d_in[0];
  const float* qkvw = (const float*)d_in[1];
  const float* ow   = (const float*)d_in[2];
  const float* f1   = (const float*)d_in[3];
  const float* f2   = (const float*)d_in[4];
  float* out = (float*)d_out;

  char* ws = (char*)d_ws;
  const size_t MB = 1024 * 1024;
  // ws layout (152 MB):
  __hip_bfloat16* xb   = (__hip_bfloat16*)(ws);             // 0..16   (alive to LN1)
  __hip_bfloat16* vals = (__hip_bfloat16*)(ws + 16 * MB);   // 16..32  (attn out, to o_proj)
  __hip_bfloat16* P1f  = (__hip_bfloat16*)(ws + 16 * MB);   // 16..32  (ff2 z=1, after vals dead)
  __hip_bfloat16* qkvT = (__hip_bfloat16*)(ws + 32 * MB);   // 32..38
  __hip_bfloat16* oT   = (__hip_bfloat16*)(ws + 38 * MB);   // 38..40
  __hip_bfloat16* f1T  = (__hip_bfloat16*)(ws + 40 * MB);   // 40..48
  __hip_bfloat16* f2T  = (__hip_bfloat16*)(ws + 48 * MB);   // 48..56
  __hip_bfloat16* qkvb = (__hip_bfloat16*)(ws + 56 * MB);   // 56..104 (to attn)
  __hip_bfloat16* P0o  = (__hip_bfloat16*)(ws + 56 * MB);   // 56..72  (after qkvb dead)
  __hip_bfloat16* P1o  = (__hip_bfloat16*)(ws + 72 * MB);   // 72..88
  __hip_bfloat16* hmid = (__hip_bfloat16*)(ws + 56 * MB);   // 56..120 (after LN1)
  __hip_bfloat16* Vt   = (__hip_bfloat16*)(ws + 104 * MB);  // 104..120 (to attn)
  __hip_bfloat16* x1b  = (__hip_bfloat16*)(ws + 120 * MB);  // 120..136 (to final LN)
  __hip_bfloat16* P0f  = (__hip_bfloat16*)(ws + 136 * MB);  // 136..152
  (void)in_sizes; (void)n_in; (void)out_size; (void)ws_size;

  // merged prep: x cast (4096 blocks, short8) + 4 weight transposes (12288)
  prep_k<<<16384, 256, 0, stream>>>(x, xb, qkvw, qkvT, ow, oT, f1, f1T, f2, f2T);
  // qkv = x @ qkv_proj (bf16; Q-cols pre-scaled; V transposed into Vt)
  gemm256<0, 1><<<dim3(32, 12, 1), 512, 0, stream>>>(xb, qkvT, qkvb, Vt,
                                                     8192, 3072, 1024);
  attn_kernel<<<dim3(32, 16), 256, 0, stream>>>(qkvb, Vt, vals);
  // o_proj partials (split-K=2, bf16)
  gemm256<4, 2><<<dim3(32, 4, 2), 512, 0, stream>>>(vals, oT, P0o, P1o,
                                                    8192, 1024, 1024);
  // x1 = LN(P0o + P1o + x) (bf16)
  ln_red_k<false><<<8192, 256, 0, stream>>>(P0o, P1o, xb, x1b, nullptr);
  // h = relu(x1 @ ff1) (bf16)
  gemm256<2, 1><<<dim3(32, 16, 1), 512, 0, stream>>>(x1b, f1T, hmid, nullptr,
                                                     8192, 4096, 1024);
  // ff2 partials (split-K=2, bf16)
  gemm256<4, 2><<<dim3(32, 4, 2), 512, 0, stream>>>(hmid, f2T, P0f, P1f,
                                                    8192, 1024, 4096);
  // out = LN(P0f + P1f + x1) (f32)
  ln_red_k<true><<<8192, 256, 0, stream>>>(P0f, P1f, x1b, nullptr, out);
}

// Round 9
// 437.663 us; speedup vs baseline: 1.0419x; 1.0211x over previous
//
#include <hip/hip_runtime.h>
#include <hip/hip_bf16.h>

// B=4, S=2048, D=1024, H=8, HD=128, FF=4096
// R16 == R13 exactly (best measured: 438.0us). R15's two edits both reverted:
//   - attn lsum-via-MFMA: VALU 47->43 as predicted but +1.5us (MFMA pipe is
//     the contended one; exp2 floor ~512cyc/kt/wave > MFMA ~320 bounds attn).
//   - prep short8 x-cast: unproven, possibly part of the +8.9 regression.
// Session wins were work-removal (V-fusion -11us) and reverts; locking best.
// R13: R9 GEMM (2-barrier/tile counted-vmcnt, XCD row-cluster remap) +
//      V^T fused into qkv epilogue (vtrans_k deleted, -32MB traffic).

typedef float floatx4 __attribute__((ext_vector_type(4)));
typedef float floatx16 __attribute__((ext_vector_type(16)));
typedef short bf16x8 __attribute__((ext_vector_type(8)));

#define DEVI __device__ __forceinline__

typedef const __attribute__((address_space(1))) unsigned int* gas1_t;
typedef __attribute__((address_space(3))) unsigned int* las3_t;

DEVI void gll16(const void* g, void* l) {
  __builtin_amdgcn_global_load_lds((gas1_t)g, (las3_t)l, 16, 0, 0);
}

DEVI short bfbits(float f) {
  __hip_bfloat16 h = __float2bfloat16(f);
  return *reinterpret_cast<short*>(&h);
}

// pack two f32 -> two bf16 (round-half-up): 2 v_add + 1 v_perm
DEVI unsigned int packbf(float lo, float hi) {
  return __builtin_amdgcn_perm(__float_as_uint(hi) + 0x8000u,
                               __float_as_uint(lo) + 0x8000u,
                               0x07060302u);
}

// ---------------------------------------------------------------------------
// C[M,N] = A[M,K](bf16 rm) * BT[N,K](bf16 rm). 256x256 tile, BK=64,
// 512 threads = 8 waves (2M x 4N), per-wave C = 128x64.
// LDS 128KB: A-half slots Ah[h][buf] (16KB), B-half slots Bh[h][buf] (16KB).
// Per tile t (cb = t&1):
//   half1: issue Ah1(t+1)->nb; ds_read Ah0+B (16); MFMA m0-3 (32); barrier
//   half2: issue Ah0(t+2),B(t+2)->cb; ds_read Ah1 (8); MFMA m4-7 (32);
//          vmcnt(6) [tile t+1 resident, 6 newest stay in flight]; barrier
// XCD remap: xcd owns gx/8 consecutive rows, sweeps cols col-major.
// EPI 0: C bf16, Q-cols pre-scaled; V-cols transposed into Vt (=Cb2)
// EPI 2: relu | EPI 4: split-K partial
// ---------------------------------------------------------------------------
template<int EPI, int SPLITK>
__global__ __launch_bounds__(512, 2) void gemm256(
    const __hip_bfloat16* __restrict__ A,
    const __hip_bfloat16* __restrict__ BT,
    __hip_bfloat16* __restrict__ Cb, __hip_bfloat16* __restrict__ Cb2,
    int M, int N, int K)
{
  __shared__ __align__(16) char lds[131072];
  const int tid = threadIdx.x;
  const int wave = tid >> 6, lane = tid & 63;
  const int lane15 = lane & 15, quad = lane >> 4;
  const int wm = wave >> 2, wn = wave & 3;            // 2 x 4 waves

  // XCD-clustered tile remap (requires gridDim.x % 8 == 0; holds: gx=32)
  const int gx = gridDim.x;
  const int rpx = gx >> 3;                            // rows per XCD
  const int flat = blockIdx.x + gx * blockIdx.y;
  const int xcd = flat & 7;
  const int ii  = flat >> 3;
  const int row0 = (xcd * rpx + (ii % rpx)) * 256;
  const int col0 = (ii / rpx) * 256;

  const int Kh = K / SPLITK;
  const size_t kofs = (SPLITK > 1) ? (size_t)blockIdx.z * Kh : 0;
  const int NT = Kh >> 6;

  floatx4 acc[8][4] = {};

  // staging: 512 thr x 16B = 8KB = 64 rows of 128B per issue
  const int srow = tid >> 3;                          // 0..63
  const int sblk = (tid & 7) ^ (srow & 7);            // chunk XOR swizzle
  const __hip_bfloat16* Ag = A + (size_t)(row0 + srow) * K + kofs + sblk * 8;
  const __hip_bfloat16* Bg = BT + (size_t)(col0 + srow) * K + kofs + sblk * 8;

  // A-half h, M-part p (0: wm=0 rows, 1: wm=1 rows), K-tile kt, buffer bf_
  auto stA = [&](int h, int p, int kt, int bf_) {
    gll16(Ag + (size_t)(p * 128 + h * 64) * (size_t)K + (size_t)kt * 64,
          lds + ((h << 1) + bf_) * 16384 + p * 8192 + (tid << 4));
  };
  // B-half h (BT rows h*128..), quarter q, K-tile kt, buffer bf_
  auto stB = [&](int h, int q, int kt, int bf_) {
    gll16(Bg + (size_t)(h * 128 + q * 64) * (size_t)K + (size_t)kt * 64,
          lds + 65536 + ((h << 1) + bf_) * 16384 + q * 8192 + (tid << 4));
  };

  // fragment read geometry
  const int x7 = lane15 & 7;
  const int ck0 = (quad ^ x7) << 4;
  const int ck1 = ((4 + quad) ^ x7) << 4;
  const int aoff = (wm * 64 + lane15) * 128;          // within A-half slot
  const int boff = ((wn & 1) * 64 + lane15) * 128;    // within B-half slot
  const int bhalf = wn >> 1;

  // ---- prologue: tile0 complete + Ah0(1),B(1) left in flight ----
  stA(0, 0, 0, 0); stA(0, 1, 0, 0);                   // Ah0(0)
  stA(1, 0, 0, 0); stA(1, 1, 0, 0);                   // Ah1(0)
  stB(0, 0, 0, 0); stB(0, 1, 0, 0); stB(1, 0, 0, 0); stB(1, 1, 0, 0); // B(0)
  stA(0, 0, 1, 1); stA(0, 1, 1, 1);                   // Ah0(1)
  stB(0, 0, 1, 1); stB(0, 1, 1, 1); stB(1, 0, 1, 1); stB(1, 1, 1, 1); // B(1)
  asm volatile("s_waitcnt vmcnt(6)" ::: "memory");    // tile0 resident
  asm volatile("s_barrier" ::: "memory");

  for (int t = 0; t < NT; ++t) {
    const int cb = t & 1, nb = cb ^ 1;
    const char* As0 = lds + cb * 16384 + aoff;              // Ah0 slot
    const char* As1 = lds + (2 + cb) * 16384 + aoff;        // Ah1 slot
    const char* Bs_ = lds + 65536 + ((bhalf << 1) + cb) * 16384 + boff;

    // ---------------- half 1: m0-3 (reads Ah0[cb], B[cb]) ----------------
    if (t + 1 < NT) { stA(1, 0, t + 1, nb); stA(1, 1, t + 1, nb); } // Ah1(t+1)
    bf16x8 af[8], bq[8];
#pragma unroll
    for (int i = 0; i < 4; i++) {
      af[2 * i]     = *(const bf16x8*)(As0 + i * 2048 + ck0);
      af[2 * i + 1] = *(const bf16x8*)(As0 + i * 2048 + ck1);
    }
#pragma unroll
    for (int j = 0; j < 4; j++) {
      bq[2 * j]     = *(const bf16x8*)(Bs_ + j * 2048 + ck0);
      bq[2 * j + 1] = *(const bf16x8*)(Bs_ + j * 2048 + ck1);
    }
    __builtin_amdgcn_s_setprio(1);
#pragma unroll
    for (int i = 0; i < 4; i++)
#pragma unroll
      for (int j = 0; j < 4; j++) {
        acc[i][j] = __builtin_amdgcn_mfma_f32_16x16x32_bf16(af[2 * i],     bq[2 * j],     acc[i][j], 0, 0, 0);
        acc[i][j] = __builtin_amdgcn_mfma_f32_16x16x32_bf16(af[2 * i + 1], bq[2 * j + 1], acc[i][j], 0, 0, 0);
      }
    __builtin_amdgcn_s_setprio(0);
    asm volatile("s_barrier" ::: "memory");   // Ah0[cb],B[cb] reads done blockwide

    // ---------------- half 2: m4-7 (reads Ah1[cb]) ----------------
    if (t + 2 < NT) {
      stA(0, 0, t + 2, cb); stA(0, 1, t + 2, cb);                  // Ah0(t+2)
      stB(0, 0, t + 2, cb); stB(0, 1, t + 2, cb);
      stB(1, 0, t + 2, cb); stB(1, 1, t + 2, cb);                  // B(t+2)
    }
#pragma unroll
    for (int i = 0; i < 4; i++) {
      af[2 * i]     = *(const bf16x8*)(As1 + i * 2048 + ck0);
      af[2 * i + 1] = *(const bf16x8*)(As1 + i * 2048 + ck1);
    }
    __builtin_amdgcn_s_setprio(1);
#pragma unroll
    for (int i = 0; i < 4; i++)
#pragma unroll
      for (int j = 0; j < 4; j++) {
        acc[4 + i][j] = __builtin_amdgcn_mfma_f32_16x16x32_bf16(af[2 * i],     bq[2 * j],     acc[4 + i][j], 0, 0, 0);
        acc[4 + i][j] = __builtin_amdgcn_mfma_f32_16x16x32_bf16(af[2 * i + 1], bq[2 * j + 1], acc[4 + i][j], 0, 0, 0);
      }
    __builtin_amdgcn_s_setprio(0);
    if (t + 2 < NT) {
      asm volatile("s_waitcnt vmcnt(6)" ::: "memory");  // tile t+1 resident
    } else if (t + 1 < NT) {
      asm volatile("s_waitcnt vmcnt(0)" ::: "memory");  // tail: drain
    }
    asm volatile("s_barrier" ::: "memory");
  }

  // -------------------------- epilogue --------------------------
  __hip_bfloat16* Cp = (SPLITK > 1 && blockIdx.z) ? Cb2 : Cb;

  // qkv only: V-column detection (col0 % 768: 256 -> V=[0,128), 512 -> [128,256))
  int vstart = -1;
  bool vwave = false;
  if (EPI == 0) {
    const int cm = col0 % 768;
    vstart = (cm == 256) ? 0 : (cm == 512 ? 128 : -1);
    vwave = (vstart == 0) ? (wn < 2) : (vstart == 128 ? (wn >= 2) : false);
  }

  if (!(EPI == 0 && vwave)) {
#pragma unroll
    for (int i = 0; i < 8; i++) {
      const int mb = row0 + wm * 128 + i * 16 + quad * 4;
#pragma unroll
      for (int j = 0; j < 4; j++) {
        const int n = col0 + wn * 64 + j * 16 + lane15;
        // qkv only: scale Q-columns by 1/sqrt(128)*log2(e) for exp2 softmax
        const float fac = (EPI == 0 && (((n >> 7) % 3) == 0)) ? 0.12751729f : 1.f;
#pragma unroll
        for (int r = 0; r < 4; r++) {
          const size_t idx = (size_t)(mb + r) * N + n;
          const float v = acc[i][j][r];
          if (EPI == 0) {
            Cb[idx] = __float2bfloat16(v * fac);
          } else if (EPI == 2) {
            Cb[idx] = __float2bfloat16(v > 0.f ? v : 0.f);
          } else {
            Cp[idx] = __float2bfloat16(v);
          }
        }
      }
    }
  }

  if (EPI == 0 && vstart >= 0) {
    // V-transpose bounce: LDS[d][sloc] (d=0..127, sloc=0..255), 512B rows,
    // byte addr = d*512 + ((sloc*2) ^ ((d&7)<<4)); 16B-granule XOR keeps
    // 8B groups contiguous. Writes <=2-way banked; reads are a permutation
    // of a contiguous 512B row -> conflict-free; stores 8B-coalesced.
    if (vwave) {
      const int dbase = wn * 64 - vstart;   // 0 or 64
#pragma unroll
      for (int i = 0; i < 8; i++) {
        const int sloc = wm * 128 + i * 16 + quad * 4;
#pragma unroll
        for (int j = 0; j < 4; j++) {
          const int d = dbase + j * 16 + lane15;
          uint2 pk;
          pk.x = packbf(acc[i][j][0], acc[i][j][1]);
          pk.y = packbf(acc[i][j][2], acc[i][j][3]);
          *(uint2*)(lds + d * 512 + ((sloc * 2) ^ ((d & 7) << 4))) = pk;
        }
      }
    }
    asm volatile("s_barrier" ::: "memory");   // V tile resident in LDS
    const int b_ = row0 >> 11;                // batch
    const int s0 = row0 & 2047;               // token offset within batch
    const int hv = (col0 + vstart) / 384;     // head
    __hip_bfloat16* vtb = Cb2 + ((size_t)(b_ * 8 + hv) * 128) * 2048 + s0;
#pragma unroll
    for (int p = 0; p < 16; p++) {
      const int d = p * 8 + wave;             // wave reads one d-row per pass
      const uint2 v8 = *(const uint2*)(lds + d * 512 + ((lane * 8) ^ ((d & 7) << 4)));
      *(uint2*)(vtb + (size_t)d * 2048 + lane * 4) = v8;
    }
  }
}

// ---------------------------------------------------------------------------
// Flash attention, pipelined. Grid (32 bh, 16 qt), bh-major -> XCD locality.
// 4 waves; wave owns 32 q (q = wave*32 + l31). S^T = K*Q^T with K-tile rows
// staged bit2<->bit3-permuted: pf built fully in-lane. Q pre-scaled in qkv
// GEMM -> p = exp2(s) directly. 2 barriers/kt. (R7 version, verified 89.7us)
// ---------------------------------------------------------------------------
__global__ __launch_bounds__(256, 2) void attn_kernel(
    const __hip_bfloat16* __restrict__ qkv,
    const __hip_bfloat16* __restrict__ Vt,
    __hip_bfloat16* __restrict__ vals)
{
  __shared__ __hip_bfloat16 Ak[128 * 128];   // K tiles (row-permuted)
  __shared__ __hip_bfloat16 Bq[128 * 128];   // Q, then V tiles

  const int tid = threadIdx.x;
  const int wave = tid >> 6, lane = tid & 63;
  const int l31 = lane & 31, l5 = lane >> 5;
  const int bh = blockIdx.x, qt = blockIdx.y;
  const int b = bh >> 3, h = bh & 7;
  const size_t tokbase = (size_t)b * 2048;

  const int sw8 = ((tid & 15) ^ (tid >> 4)) * 8;
  const int srow = tid >> 4;
  // bit2<->bit3 swap of the tile-local staging row (K only)
  const int srowp = (srow & 3) | ((srow << 1) & 8) | ((srow >> 1) & 4);
  const __hip_bfloat16* qg  = qkv + (tokbase + qt * 128) * 3072 + h * 384 + sw8;
  const __hip_bfloat16* kg0 = qkv + tokbase * 3072 + h * 384 + 128 + sw8;
  const __hip_bfloat16* vg0 = Vt + (size_t)bh * 128 * 2048 + sw8;

  // stage Q -> Bq
#pragma unroll
  for (int rd = 0; rd < 8; rd++)
    gll16(qg + (size_t)(rd * 16 + srow) * 3072, (char*)Bq + rd * 4096 + tid * 16);
  __syncthreads();

  const int rx = l31 & 15;
  bf16x8 qf[8];
  {
    const char* qb = (const char*)Bq + (wave * 32 + l31) * 256;
#pragma unroll
    for (int ks = 0; ks < 8; ks++)
      qf[ks] = *(const bf16x8*)(qb + (((ks * 2 + l5) ^ rx) << 4));
  }
  // stage K0 -> Ak (permuted rows)
#pragma unroll
  for (int rd = 0; rd < 8; rd++)
    gll16(kg0 + (size_t)(rd * 16 + srowp) * 3072, (char*)Ak + rd * 4096 + tid * 16);
  __syncthreads();   // qf reads done, K0 resident

  floatx16 oacc[4] = {};
  float lsum = 0.f;

  for (int kt = 0; kt < 16; kt++) {
    if (kt) __syncthreads();   // PV reads of Bq done; K_kt staging drained

    // issue V_kt -> Bq; overlaps QK + softmax below
#pragma unroll
    for (int rd = 0; rd < 8; rd++)
      gll16(vg0 + (size_t)kt * 128 + (size_t)(rd * 16 + srow) * 2048,
            (char*)Bq + rd * 4096 + tid * 16);

    // S^T = K Q^T : D[s][q], col q = l31
    floatx16 sacc[4] = {};
#pragma unroll
    for (int ks = 0; ks < 8; ks++) {
      const int off = ((ks * 2 + l5) ^ rx) << 4;
      const char* kb = (const char*)Ak + l31 * 256 + off;
#pragma unroll
      for (int nt = 0; nt < 4; nt++) {
        const bf16x8 ak = *(const bf16x8*)(kb + nt * 8192);
        sacc[nt] = __builtin_amdgcn_mfma_f32_32x32x16_bf16(ak, qf[ks], sacc[nt], 0, 0, 0);
      }
    }

    // p = exp2(s); in-lane sum; in-lane B-frag construction (key perm)
    bf16x8 pf[8];
#pragma unroll
    for (int c = 0; c < 8; c++) {
      const int nt = c >> 1, bi = (c & 1) * 8;
      const float p0 = exp2f(sacc[nt][bi + 0]);
      const float p1 = exp2f(sacc[nt][bi + 1]);
      const float p2 = exp2f(sacc[nt][bi + 2]);
      const float p3 = exp2f(sacc[nt][bi + 3]);
      const float p4 = exp2f(sacc[nt][bi + 4]);
      const float p5 = exp2f(sacc[nt][bi + 5]);
      const float p6 = exp2f(sacc[nt][bi + 6]);
      const float p7 = exp2f(sacc[nt][bi + 7]);
      lsum += ((p0 + p1) + (p2 + p3)) + ((p4 + p5) + (p6 + p7));
      union { uint4 u; bf16x8 v; } w;
      w.u.x = packbf(p0, p1); w.u.y = packbf(p2, p3);
      w.u.z = packbf(p4, p5); w.u.w = packbf(p6, p7);
      pf[c] = w.v;
    }

    __syncthreads();   // V_kt resident; QK reads of Ak done
    if (kt < 15) {     // issue K_{kt+1} -> Ak; overlaps PV below
#pragma unroll
      for (int rd = 0; rd < 8; rd++)
        gll16(kg0 + (size_t)((kt + 1) * 128 + rd * 16 + srowp) * 3072,
              (char*)Ak + rd * 4096 + tid * 16);
    }

    // O^T[hd][q] += V^T P^T : A = Vt rows hd (Bq), B = pf
#pragma unroll
    for (int ks = 0; ks < 8; ks++) {
      const int off = ((ks * 2 + l5) ^ rx) << 4;
      const char* vb = (const char*)Bq + l31 * 256 + off;
#pragma unroll
      for (int nt = 0; nt < 4; nt++) {
        const bf16x8 av = *(const bf16x8*)(vb + nt * 8192);
        oacc[nt] = __builtin_amdgcn_mfma_f32_32x32x16_bf16(av, pf[ks], oacc[nt], 0, 0, 0);
      }
    }
  }

  lsum += __shfl_xor(lsum, 32);
  const float linv = 1.f / lsum;

  // D layout: col q = l31, row hd = 32nt + 8g + 4l5 + r3 -> 8B stores
  const size_t row = tokbase + (size_t)qt * 128 + wave * 32 + l31;
  __hip_bfloat16* vrow = vals + row * 1024 + h * 128 + 4 * l5;
#pragma unroll
  for (int nt = 0; nt < 4; nt++)
#pragma unroll
    for (int g = 0; g < 4; g++) {
      uint2 pk;
      pk.x = packbf(oacc[nt][g * 4 + 0] * linv, oacc[nt][g * 4 + 1] * linv);
      pk.y = packbf(oacc[nt][g * 4 + 2] * linv, oacc[nt][g * 4 + 3] * linv);
      *(uint2*)(vrow + nt * 32 + g * 8) = pk;
    }
}

// --------------------------- aux kernels -----------------------------------
// Merged prep: blocks [0,8192) cast x to bf16; rest transpose+cast weights.
__global__ __launch_bounds__(256) void prep_k(
    const float* __restrict__ x, __hip_bfloat16* __restrict__ xb,
    const float* __restrict__ qkvw, __hip_bfloat16* __restrict__ qkvT,
    const float* __restrict__ ow, __hip_bfloat16* __restrict__ oT,
    const float* __restrict__ f1, __hip_bfloat16* __restrict__ f1T,
    const float* __restrict__ f2, __hip_bfloat16* __restrict__ f2T)
{
  const int bid = blockIdx.x;
  if (bid < 8192) {
    const size_t i = (size_t)bid * 256 + threadIdx.x;
    const float4 v = ((const float4*)x)[i];
    short4 sv;
    sv.x = bfbits(v.x); sv.y = bfbits(v.y); sv.z = bfbits(v.z); sv.w = bfbits(v.w);
    ((short4*)xb)[i] = sv;
    return;
  }
  int t = bid - 8192;
  const float* W; __hip_bfloat16* WT; int K, N, nbx;
  if (t < 3072) { W = qkvw; WT = qkvT; K = 1024; N = 3072; nbx = 96; }
  else if (t < 3072 + 1024) { t -= 3072; W = ow; WT = oT; K = 1024; N = 1024; nbx = 32; }
  else if (t < 3072 + 1024 + 4096) { t -= 3072 + 1024; W = f1; WT = f1T; K = 1024; N = 4096; nbx = 128; }
  else { t -= 3072 + 1024 + 4096; W = f2; WT = f2T; K = 4096; N = 1024; nbx = 32; }
  __shared__ float tl[32][33];
  const int tx = threadIdx.x & 31, ty = threadIdx.x >> 5;
  const int n0 = (t % nbx) * 32, k0 = (t / nbx) * 32;
#pragma unroll
  for (int i = 0; i < 4; i++)
    tl[ty + i * 8][tx] = W[(size_t)(k0 + ty + i * 8) * N + n0 + tx];
  __syncthreads();
#pragma unroll
  for (int i = 0; i < 4; i++)
    WT[(size_t)(n0 + ty + i * 8) * K + k0 + tx] = __float2bfloat16(tl[tx][ty + i * 8]);
}

// Fused split-K reduce (bf16 partials) + bf16 residual + LayerNorm over 1024.
template<bool FINAL>
__global__ __launch_bounds__(256) void ln_red_k(
    const __hip_bfloat16* __restrict__ p0, const __hip_bfloat16* __restrict__ p1,
    const __hip_bfloat16* __restrict__ res,
    __hip_bfloat16* __restrict__ ob, float* __restrict__ of) {
  const int row = blockIdx.x, tid = threadIdx.x;
  const size_t base = (size_t)row * 1024;
  const short4 a4 = ((const short4*)(p0 + base))[tid];
  const short4 b4 = ((const short4*)(p1 + base))[tid];
  const short4 r4 = ((const short4*)(res + base))[tid];
#define BF(x) __bfloat162float(*(const __hip_bfloat16*)&(x))
  float4 v;
  v.x = BF(a4.x) + BF(b4.x) + BF(r4.x);
  v.y = BF(a4.y) + BF(b4.y) + BF(r4.y);
  v.z = BF(a4.z) + BF(b4.z) + BF(r4.z);
  v.w = BF(a4.w) + BF(b4.w) + BF(r4.w);
#undef BF
  float s = v.x + v.y + v.z + v.w;
  float q = v.x * v.x + v.y * v.y + v.z * v.z + v.w * v.w;
#pragma unroll
  for (int off = 32; off; off >>= 1) { s += __shfl_xor(s, off); q += __shfl_xor(q, off); }
  __shared__ float ss[4], sq[4];
  const int wave = tid >> 6;
  if ((tid & 63) == 0) { ss[wave] = s; sq[wave] = q; }
  __syncthreads();
  s = ss[0] + ss[1] + ss[2] + ss[3];
  q = sq[0] + sq[1] + sq[2] + sq[3];
  const float mean = s * (1.f / 1024.f);
  const float var = q * (1.f / 1024.f) - mean * mean;
  const float rstd = rsqrtf(var + 1e-5f);
  float4 o;
  o.x = (v.x - mean) * rstd; o.y = (v.y - mean) * rstd;
  o.z = (v.z - mean) * rstd; o.w = (v.w - mean) * rstd;
  if (FINAL) {
    ((float4*)(of + base))[tid] = o;
  } else {
    short4 sv;
    sv.x = bfbits(o.x); sv.y = bfbits(o.y); sv.z = bfbits(o.z); sv.w = bfbits(o.w);
    ((short4*)(ob + base))[tid] = sv;
  }
}

// ---------------------------------------------------------------------------
extern "C" void kernel_launch(void* const* d_in, const int* in_sizes, int n_in,
                              void* d_out, int out_size, void* d_ws, size_t ws_size,
                              hipStream_t stream) {
  const float* x    = (const float*)d_in[0];
  const float* qkvw = (const float*)d_in[1];
  const float* ow   = (const float*)d_in[2];
  const float* f1   = (const float*)d_in[3];
  const float* f2   = (const float*)d_in[4];
  float* out = (float*)d_out;

  char* ws = (char*)d_ws;
  const size_t MB = 1024 * 1024;
  // ws layout (152 MB):
  __hip_bfloat16* xb   = (__hip_bfloat16*)(ws);             // 0..16   (alive to LN1)
  __hip_bfloat16* vals = (__hip_bfloat16*)(ws + 16 * MB);   // 16..32  (attn out, to o_proj)
  __hip_bfloat16* P1f  = (__hip_bfloat16*)(ws + 16 * MB);   // 16..32  (ff2 z=1, after vals dead)
  __hip_bfloat16* qkvT = (__hip_bfloat16*)(ws + 32 * MB);   // 32..38
  __hip_bfloat16* oT   = (__hip_bfloat16*)(ws + 38 * MB);   // 38..40
  __hip_bfloat16* f1T  = (__hip_bfloat16*)(ws + 40 * MB);   // 40..48
  __hip_bfloat16* f2T  = (__hip_bfloat16*)(ws + 48 * MB);   // 48..56
  __hip_bfloat16* qkvb = (__hip_bfloat16*)(ws + 56 * MB);   // 56..104 (to attn)
  __hip_bfloat16* P0o  = (__hip_bfloat16*)(ws + 56 * MB);   // 56..72  (after qkvb dead)
  __hip_bfloat16* P1o  = (__hip_bfloat16*)(ws + 72 * MB);   // 72..88
  __hip_bfloat16* hmid = (__hip_bfloat16*)(ws + 56 * MB);   // 56..120 (after LN1)
  __hip_bfloat16* Vt   = (__hip_bfloat16*)(ws + 104 * MB);  // 104..120 (to attn)
  __hip_bfloat16* x1b  = (__hip_bfloat16*)(ws + 120 * MB);  // 120..136 (to final LN)
  __hip_bfloat16* P0f  = (__hip_bfloat16*)(ws + 136 * MB);  // 136..152
  (void)in_sizes; (void)n_in; (void)out_size; (void)ws_size;

  // merged prep: x cast (8192 blocks) + 4 weight transposes (12288 blocks)
  prep_k<<<20480, 256, 0, stream>>>(x, xb, qkvw, qkvT, ow, oT, f1, f1T, f2, f2T);
  // qkv = x @ qkv_proj (bf16; Q-cols pre-scaled; V transposed into Vt)
  gemm256<0, 1><<<dim3(32, 12, 1), 512, 0, stream>>>(xb, qkvT, qkvb, Vt,
                                                     8192, 3072, 1024);
  attn_kernel<<<dim3(32, 16), 256, 0, stream>>>(qkvb, Vt, vals);
  // o_proj partials (split-K=2, bf16)
  gemm256<4, 2><<<dim3(32, 4, 2), 512, 0, stream>>>(vals, oT, P0o, P1o,
                                                    8192, 1024, 1024);
  // x1 = LN(P0o + P1o + x) (bf16)
  ln_red_k<false><<<8192, 256, 0, stream>>>(P0o, P1o, xb, x1b, nullptr);
  // h = relu(x1 @ ff1) (bf16)
  gemm256<2, 1><<<dim3(32, 16, 1), 512, 0, stream>>>(x1b, f1T, hmid, nullptr,
                                                     8192, 4096, 1024);
  // ff2 partials (split-K=2, bf16)
  gemm256<4, 2><<<dim3(32, 4, 2), 512, 0, stream>>>(hmid, f2T, P0f, P1f,
                                                    8192, 1024, 4096);
  // out = LN(P0f + P1f + x1) (f32)
  ln_red_k<true><<<8192, 256, 0, stream>>>(P0f, P1f, x1b, nullptr, out);
}